// Round 5
// baseline (252.767 us; speedup 1.0000x reference)
//
#include <hip/hip_runtime.h>
#include <hip/hip_bf16.h>

#define NPX 16384
using bf16 = __hip_bfloat16;
typedef __attribute__((ext_vector_type(8))) short short8;
typedef __attribute__((ext_vector_type(4))) float f32x4;

#define DEV static __device__ __forceinline__

// wt layout (shorts)
#define WAB   0
#define WINW  4096
#define W1HI  8192
#define W1LO  16384
#define W2HI  24576
#define W2LO  40960
#define W3HI  57344
#define W3LO  65536
#define WQT   73728
#define WKV   77824
#define WTOT  86016

DEV float lrelu(float v) { return v >= 0.f ? v : 0.01f * v; }
DEV short f2b(float f) { __hip_bfloat16 h = __float2bfloat16(f); return *reinterpret_cast<short*>(&h); }
DEV float b2f(short s) { __hip_bfloat16 h; *reinterpret_cast<short*>(&h) = s; return __bfloat162float(h); }
DEV f32x4 mfma16(short8 a, short8 b, f32x4 c) {
    return __builtin_amdgcn_mfma_f32_16x16x32_bf16(a, b, c, 0, 0, 0);
}

// ---------------------------------------------------------------------------
// Single-m-tile (16 px) GEMM: acc[t] += A[16xK] * WT[t*16..][K]^T
// ---------------------------------------------------------------------------
template<int K, int NT>
DEV void gemm1(const short* __restrict__ A, int pitch,
               const short* __restrict__ WT, f32x4* acc)
{
    int lane = threadIdx.x & 63;
    int ln = lane & 15, q8 = (lane >> 4) * 8;
    const short* ap = A + (size_t)ln * pitch + q8;
    const short* bp = WT + ln * K + q8;
#pragma unroll
    for (int c0 = 0; c0 < K; c0 += 32) {
        short8 a = *(const short8*)(ap + c0);
#pragma unroll
        for (int t = 0; t < NT; ++t) {
            short8 b = *(const short8*)(bp + (size_t)t * 16 * K + c0);
            acc[t] = mfma16(a, b, acc[t]);
        }
    }
}

template<int NT>
DEV void acc_bias1(f32x4* acc, const float* __restrict__ bias)
{
    int ln = threadIdx.x & 15;
#pragma unroll
    for (int t = 0; t < NT; ++t) {
        float bv = bias[t * 16 + ln];
        f32x4 v = {bv, bv, bv, bv};
        acc[t] = v;
    }
}

// D layout: col=lane&15, row=(lane>>4)*4+reg  -> LDS [16][pitch] bf16
template<int NT>
DEV void dstore1(const f32x4* acc, short* sD, int pitch)
{
    int lane = threadIdx.x & 63;
    int ln = lane & 15, r0 = (lane >> 4) * 4;
#pragma unroll
    for (int t = 0; t < NT; ++t)
#pragma unroll
        for (int r = 0; r < 4; ++r)
            sD[(r0 + r) * pitch + t * 16 + ln] = f2b(acc[t][r]);
}

// split fp32 acc -> hi/lo bf16 LDS tiles
template<int NT>
DEV void split_store(const f32x4* acc, short* hi, short* lo, int pitch)
{
    int lane = threadIdx.x & 63;
    int ln = lane & 15, r0 = (lane >> 4) * 4;
#pragma unroll
    for (int t = 0; t < NT; ++t)
#pragma unroll
        for (int r = 0; r < 4; ++r) {
            float v = acc[t][r];
            short h = f2b(v);
            hi[(r0 + r) * pitch + t * 16 + ln] = h;
            lo[(r0 + r) * pitch + t * 16 + ln] = f2b(v - b2f(h));
        }
}

// in-register LayerNorm(+lrelu) over 128 channels from fp32 accumulators
template<int NT>
DEV void ln_reg(f32x4* acc, const float* __restrict__ g, const float* __restrict__ be)
{
    int lane = threadIdx.x & 63, ln = lane & 15;
    f32x4 s = {0,0,0,0}, ss = {0,0,0,0};
#pragma unroll
    for (int t = 0; t < NT; ++t)
#pragma unroll
        for (int r = 0; r < 4; ++r) { float v = acc[t][r]; s[r] += v; ss[r] += v * v; }
#pragma unroll
    for (int off = 1; off < 16; off <<= 1)
#pragma unroll
        for (int r = 0; r < 4; ++r) {
            s[r] += __shfl_xor(s[r], off);
            ss[r] += __shfl_xor(ss[r], off);
        }
    f32x4 mm, rs;
#pragma unroll
    for (int r = 0; r < 4; ++r) {
        float m = s[r] * (1.f / 128.f);
        float var = ss[r] * (1.f / 128.f) - m * m;
        mm[r] = m; rs[r] = rsqrtf(var + 1e-5f);
    }
#pragma unroll
    for (int t = 0; t < NT; ++t) {
        float gg = g[t * 16 + ln], bb = be[t * 16 + ln];
#pragma unroll
        for (int r = 0; r < 4; ++r)
            acc[t][r] = lrelu((acc[t][r] - mm[r]) * rs[r] * gg + bb);
    }
}

// wave-level copyout of 16x64 bf16 tile -> global [px][64]
DEV void copyout16(const short* sD, int pitch, short* __restrict__ dst)
{
    int lane = threadIdx.x & 63;
    int px = lane >> 2, c = (lane & 3) * 16;
    short8 v0 = *(const short8*)(&sD[px * pitch + c]);
    short8 v1 = *(const short8*)(&sD[px * pitch + c + 8]);
    *reinterpret_cast<short8*>(dst + (size_t)px * 64 + c) = v0;
    *reinterpret_cast<short8*>(dst + (size_t)px * 64 + c + 8) = v1;
}

// stage 16 px of x (fp32 channel-major) -> wave LDS [16][72] bf16 (plain)
DEV void stage_x16(const float* __restrict__ xb, int n0, short* X)
{
    int lane = threadIdx.x & 63;
    int ln = lane & 15, qd = lane >> 4;
    float vb[16];
#pragma unroll
    for (int t = 0; t < 16; ++t) vb[t] = xb[(size_t)(qd * 16 + t) * NPX + n0 + ln];
    short8 lo, hi;
#pragma unroll
    for (int t = 0; t < 8; ++t) { lo[t] = f2b(vb[t]); hi[t] = f2b(vb[8 + t]); }
    *reinterpret_cast<short8*>(&X[ln * 72 + qd * 16]) = lo;
    *reinterpret_cast<short8*>(&X[ln * 72 + qd * 16 + 8]) = hi;
}

// stage x split into hi/lo bf16 (compensated)
DEV void stage_x16_split(const float* __restrict__ xb, int n0, short* Xhi, short* Xlo)
{
    int lane = threadIdx.x & 63;
    int ln = lane & 15, qd = lane >> 4;
    float vb[16];
#pragma unroll
    for (int t = 0; t < 16; ++t) vb[t] = xb[(size_t)(qd * 16 + t) * NPX + n0 + ln];
    short8 h0, h1, l0, l1;
#pragma unroll
    for (int t = 0; t < 8; ++t) {
        float v = vb[t];     short h = f2b(v); h0[t] = h; l0[t] = f2b(v - b2f(h));
        float v2 = vb[8 + t]; short h2 = f2b(v2); h1[t] = h2; l1[t] = f2b(v2 - b2f(h2));
    }
    *reinterpret_cast<short8*>(&Xhi[ln * 72 + qd * 16]) = h0;
    *reinterpret_cast<short8*>(&Xhi[ln * 72 + qd * 16 + 8]) = h1;
    *reinterpret_cast<short8*>(&Xlo[ln * 72 + qd * 16]) = l0;
    *reinterpret_cast<short8*>(&Xlo[ln * 72 + qd * 16 + 8]) = l1;
}

// ---------------------------------------------------------------------------
// k_prep: transposed bf16 weights (hi/lo split for MLP chain)
// ---------------------------------------------------------------------------
DEV float wlo(float w) { return w - b2f(f2b(w)); }

__global__ __launch_bounds__(256) void k_prep(const float* __restrict__ wa,
                                              const float* __restrict__ wb,
                                              const float* __restrict__ in_w,
                                              const float* __restrict__ w1,
                                              const float* __restrict__ w2,
                                              const float* __restrict__ w3,
                                              const float* __restrict__ wq,
                                              const float* __restrict__ wk,
                                              const float* __restrict__ wv,
                                              short* __restrict__ wt)
{
    int idx = blockIdx.x * 256 + threadIdx.x;
    if (idx >= WTOT) return;
    float v;
    if (idx < WINW) {
        int j = idx >> 6, c = idx & 63;
        v = (j < 4) ? wa[c * 4 + j] : wb[((j - 4) / 3) * 192 + c * 3 + ((j - 4) % 3)];
    } else if (idx < W1HI) {
        int i = idx - WINW; v = in_w[(i & 63) * 64 + (i >> 6)];
    } else if (idx < W1LO) {
        int i = idx - W1HI; v = w1[(i & 63) * 128 + (i >> 6)];
    } else if (idx < W2HI) {
        int i = idx - W1LO; v = wlo(w1[(i & 63) * 128 + (i >> 6)]);
    } else if (idx < W2LO) {
        int i = idx - W2HI; v = w2[(i & 127) * 128 + (i >> 7)];
    } else if (idx < W3HI) {
        int i = idx - W2LO; v = wlo(w2[(i & 127) * 128 + (i >> 7)]);
    } else if (idx < W3LO) {
        int i = idx - W3HI; v = w3[(i & 127) * 64 + (i >> 7)];
    } else if (idx < WQT) {
        int i = idx - W3LO; v = wlo(w3[(i & 127) * 64 + (i >> 7)]);
    } else if (idx < WKV) {
        int i = idx - WQT; v = wq[(i & 63) * 64 + (i >> 6)];
    } else {
        int i = idx - WKV; int e = i >> 6, k = i & 63;
        v = (e < 64) ? wk[k * 64 + e] : wv[k * 64 + (e - 64)];
    }
    wt[idx] = f2b(v);
}

// ---------------------------------------------------------------------------
// k_fyk: x,sem -> feat -> y -> k,v   (barrier-free, per-wave LDS, plain bf16)
// ---------------------------------------------------------------------------
__global__ __launch_bounds__(256) void k_fyk(const float* __restrict__ x,
                                             const float* __restrict__ sem,
                                             const float* __restrict__ ba,
                                             const float* __restrict__ bbv,
                                             const float* __restrict__ in_b,
                                             const float* __restrict__ bk,
                                             const float* __restrict__ bv,
                                             const short* __restrict__ wt,
                                             short* __restrict__ kout,
                                             short* __restrict__ vout)
{
    __shared__ short smem[4][3][16 * 72];
    int tid = threadIdx.x, w = tid >> 6, lane = tid & 63;
    int ln = lane & 15, qd = lane >> 4;
    int pw = blockIdx.x * 64 + w * 16;
    int b = pw >> 14, n0 = pw & (NPX - 1);
    const float* xb = x + (size_t)b * 64 * NPX;
    short* X  = smem[w][0];
    short* S1 = smem[w][1];
    short* S2 = smem[w][2];

    stage_x16(xb, n0, X);

    f32x4 a1[4];
    { f32x4 z = {0,0,0,0}; for (int t = 0; t < 4; ++t) a1[t] = z; }
    gemm1<64, 4>(X, 72, wt + WAB, a1);
#pragma unroll
    for (int t = 0; t < 4; ++t) {
        int j = t * 16 + ln;
        int cls = (j < 4) ? 0 : 1 + (j - 4) / 3;
        float bias = (j < 4) ? ba[j] : bbv[j - 4];
        f32x4 sm4 = *(const f32x4*)(sem + ((size_t)b * 21 + cls) * NPX + n0 + qd * 4);
#pragma unroll
        for (int r = 0; r < 4; ++r)
            S1[(qd * 4 + r) * 72 + j] = f2b(fmaxf(sm4[r], 0.f) * a1[t][r] + bias);
    }

    f32x4 a2[4];
    acc_bias1<4>(a2, in_b);
    gemm1<64, 4>(S1, 72, wt + WINW, a2);
    dstore1<4>(a2, S2, 72);

    f32x4 a3[8];
    acc_bias1<4>(a3, bk);
    acc_bias1<4>(a3 + 4, bv);
    gemm1<64, 8>(S2, 72, wt + WKV, a3);
    dstore1<4>(a3, S1, 72);        // k
    dstore1<4>(a3 + 4, X, 72);     // v
    copyout16(S1, 72, kout + (size_t)pw * 64);
    copyout16(X, 72, vout + (size_t)pw * 64);
}

// ---------------------------------------------------------------------------
// k_mlp: x -> h1 -> h2 -> xm(fp32) -> q    (compensated bf16 GEMMs)
// ---------------------------------------------------------------------------
__global__ __launch_bounds__(256) void k_mlp(const float* __restrict__ x,
                                             const float* __restrict__ b1,
                                             const float* __restrict__ g1,
                                             const float* __restrict__ be1,
                                             const float* __restrict__ b2,
                                             const float* __restrict__ g2,
                                             const float* __restrict__ be2,
                                             const float* __restrict__ b3,
                                             const float* __restrict__ bq,
                                             const short* __restrict__ wt,
                                             float* __restrict__ xmout,
                                             short* __restrict__ qout)
{
    __shared__ short sX[4][2 * 16 * 72];
    __shared__ short sH[4][16 * 136];
    __shared__ short sL[4][16 * 136];
    int tid = threadIdx.x, w = tid >> 6, lane = tid & 63;
    int ln = lane & 15, qd = lane >> 4, r0 = qd * 4;
    int pw = blockIdx.x * 64 + w * 16;
    int b = pw >> 14, n0 = pw & (NPX - 1);
    const float* xb = x + (size_t)b * 64 * NPX;
    short* Xhi = sX[w];
    short* Xlo = sX[w] + 16 * 72;
    short* S1h = sH[w];
    short* S1l = sL[w];

    stage_x16_split(xb, n0, Xhi, Xlo);

    f32x4 acc[8];
    acc_bias1<8>(acc, b1);
    gemm1<64, 8>(Xhi, 72, wt + W1HI, acc);
    gemm1<64, 8>(Xhi, 72, wt + W1LO, acc);
    gemm1<64, 8>(Xlo, 72, wt + W1HI, acc);
    ln_reg<8>(acc, g1, be1);
    split_store<8>(acc, S1h, S1l, 136);

    acc_bias1<8>(acc, b2);
    gemm1<128, 8>(S1h, 136, wt + W2HI, acc);
    gemm1<128, 8>(S1h, 136, wt + W2LO, acc);
    gemm1<128, 8>(S1l, 136, wt + W2HI, acc);
    ln_reg<8>(acc, g2, be2);
    split_store<8>(acc, S1h, S1l, 136);

    f32x4 a3[4];
    acc_bias1<4>(a3, b3);
    gemm1<128, 4>(S1h, 136, wt + W3HI, a3);
    gemm1<128, 4>(S1h, 136, wt + W3LO, a3);
    gemm1<128, 4>(S1l, 136, wt + W3HI, a3);

    // xm fp32 out via LDS (reuse sX as float buffer, pitch 68)
    float* XF = (float*)sX[w];
#pragma unroll
    for (int t = 0; t < 4; ++t)
#pragma unroll
        for (int r = 0; r < 4; ++r)
            XF[(r0 + r) * 68 + t * 16 + ln] = a3[t][r];
    {
        int px = lane >> 2, c = (lane & 3) * 16;
#pragma unroll
        for (int j = 0; j < 4; ++j) {
            f32x4 vv = *(const f32x4*)(&XF[px * 68 + c + j * 4]);
            *reinterpret_cast<f32x4*>(xmout + (size_t)(pw + px) * 64 + c + j * 4) = vv;
        }
    }

    // q = bf16(xm) @ wq + bq  (plain bf16; feeds normalized gram only)
    dstore1<4>(a3, S1h, 136);
    f32x4 aq[4];
    acc_bias1<4>(aq, bq);
    gemm1<64, 4>(S1h, 136, wt + WQT, aq);
    dstore1<4>(aq, S1l, 136);
    copyout16(S1l, 136, qout + (size_t)pw * 64);
}

// ---------------------------------------------------------------------------
// k_gram: per-wave 128-px chunk; 3 MFMAs (qk, qq, kk); fp32 atomics
// ---------------------------------------------------------------------------
__global__ __launch_bounds__(256) void k_gram(const short* __restrict__ q,
                                              const short* __restrict__ k,
                                              float* __restrict__ gram,
                                              float* __restrict__ nsq)
{
    __shared__ short sQ[4][16 * 136], sK[4][16 * 136];
    int tid = threadIdx.x, w = tid >> 6, lane = tid & 63;
    int ln = lane & 15, q8 = (lane >> 4) * 8, qd = lane >> 4;
    int bh = blockIdx.x >> 5;
    int b = bh >> 2, h = bh & 3;
    int nb = (blockIdx.x & 31) * 512 + w * 128;
    size_t pxg = (size_t)b * NPX + nb;

#pragma unroll
    for (int it = 0; it < 4; ++it) {
        int idx = it * 64 + lane;
        int px = idx >> 1, half = idx & 1;
        short8 qv = *(const short8*)(q + (pxg + px) * 64 + h * 16 + half * 8);
        short8 kv = *(const short8*)(k + (pxg + px) * 64 + h * 16 + half * 8);
#pragma unroll
        for (int j = 0; j < 8; ++j) {
            sQ[w][(half * 8 + j) * 136 + px] = qv[j];
            sK[w][(half * 8 + j) * 136 + px] = kv[j];
        }
    }

    f32x4 aqk = {0,0,0,0}, aqq = {0,0,0,0}, akk = {0,0,0,0};
#pragma unroll
    for (int s = 0; s < 4; ++s) {
        short8 a  = *(const short8*)(&sQ[w][ln * 136 + s * 32 + q8]);
        short8 bb = *(const short8*)(&sK[w][ln * 136 + s * 32 + q8]);
        aqk = mfma16(a, bb, aqk);
        aqq = mfma16(a, a, aqq);
        akk = mfma16(bb, bb, akk);
    }
    int e = ln;
#pragma unroll
    for (int r = 0; r < 4; ++r) {
        int d = qd * 4 + r;
        atomicAdd(&gram[bh * 256 + d * 16 + e], aqk[r]);
        if (e == d) {
            atomicAdd(&nsq[bh * 16 + d], aqq[r]);
            atomicAdd(&nsq[256 + bh * 16 + d], akk[r]);
        }
    }
}

// ---------------------------------------------------------------------------
// k_attnM: softmax + fold wo -> MT[b][cc][he] bf16
// ---------------------------------------------------------------------------
__global__ __launch_bounds__(256) void k_attnM(const float* __restrict__ gram,
                                               const float* __restrict__ nsq,
                                               const float* __restrict__ rescale,
                                               const float* __restrict__ wo,
                                               short* __restrict__ MT)
{
    __shared__ float s_at[1024];
    int b = blockIdx.x, tid = threadIdx.x;
    if (tid < 64) {
        int h = tid >> 4, d = tid & 15;
        float nq = sqrtf(nsq[b * 64 + h * 16 + d]) + 1e-8f;
        float rsc = rescale[h];
        float lg[16];
#pragma unroll
        for (int e = 0; e < 16; ++e) {
            float nk = sqrtf(nsq[256 + b * 64 + h * 16 + e]) + 1e-8f;
            lg[e] = rsc * gram[b * 1024 + h * 256 + d * 16 + e] / (nq * nk);
        }
        float m = lg[0];
#pragma unroll
        for (int e = 1; e < 16; ++e) m = fmaxf(m, lg[e]);
        float ssum = 0.f;
#pragma unroll
        for (int e = 0; e < 16; ++e) { lg[e] = expf(lg[e] - m); ssum += lg[e]; }
        float inv = 1.f / ssum;
#pragma unroll
        for (int e = 0; e < 16; ++e) s_at[h * 256 + d * 16 + e] = lg[e] * inv;
    }
    __syncthreads();
    int he = tid >> 2, h = he >> 4, e = he & 15;
    int cc0 = (tid & 3) * 16;
#pragma unroll
    for (int cx = 0; cx < 16; ++cx) {
        int cc = cc0 + cx;
        float s = 0.f;
#pragma unroll
        for (int d = 0; d < 16; ++d)
            s = fmaf(s_at[h * 256 + d * 16 + e], wo[(h * 16 + d) * 64 + cc], s);
        MT[b * 4096 + cc * 64 + he] = f2b(s);
    }
}

// ---------------------------------------------------------------------------
// k_out: out[b][c][n] = v@M + bo + xm(fp32)   (barrier-free, no LDS)
// ---------------------------------------------------------------------------
__global__ __launch_bounds__(256) void k_out(const short* __restrict__ v,
                                             const float* __restrict__ xmf,
                                             const short* __restrict__ MT,
                                             const float* __restrict__ bo,
                                             float* __restrict__ out)
{
    int tid = threadIdx.x, w = tid >> 6, lane = tid & 63;
    int ln = lane & 15, qd = lane >> 4;
    int pw = blockIdx.x * 64 + w * 16;
    int b = pw >> 14, n0 = pw & (NPX - 1);

    f32x4 acc[4];
    acc_bias1<4>(acc, bo);
    gemm1<64, 4>(v + (size_t)pw * 64, 64, MT + b * 4096, acc);

#pragma unroll
    for (int t = 0; t < 4; ++t) {
        int c = t * 16 + ln;
        f32x4 o;
#pragma unroll
        for (int r = 0; r < 4; ++r)
            o[r] = acc[t][r] + xmf[(size_t)(pw + qd * 4 + r) * 64 + c];
        *reinterpret_cast<f32x4*>(out + ((size_t)b * 64 + c) * NPX + n0 + qd * 4) = o;
    }
}

// ---------------------------------------------------------------------------
extern "C" void kernel_launch(void* const* d_in, const int* in_sizes, int n_in,
                              void* d_out, int out_size, void* d_ws, size_t ws_size,
                              hipStream_t stream)
{
    const float* x    = (const float*)d_in[0];
    const float* sem  = (const float*)d_in[1];
    const float* wa   = (const float*)d_in[2];
    const float* ba   = (const float*)d_in[3];
    const float* wb   = (const float*)d_in[4];
    const float* bbv  = (const float*)d_in[5];
    const float* in_w = (const float*)d_in[6];
    const float* in_b = (const float*)d_in[7];
    const float* w1   = (const float*)d_in[8];
    const float* b1   = (const float*)d_in[9];
    const float* g1   = (const float*)d_in[10];
    const float* be1  = (const float*)d_in[11];
    const float* w2   = (const float*)d_in[12];
    const float* b2   = (const float*)d_in[13];
    const float* g2   = (const float*)d_in[14];
    const float* be2  = (const float*)d_in[15];
    const float* w3   = (const float*)d_in[16];
    const float* b3   = (const float*)d_in[17];
    const float* wq   = (const float*)d_in[18];
    const float* bq   = (const float*)d_in[19];
    const float* wk   = (const float*)d_in[20];
    const float* bk   = (const float*)d_in[21];
    const float* wv   = (const float*)d_in[22];
    const float* bv   = (const float*)d_in[23];
    const float* wo   = (const float*)d_in[24];
    const float* bo   = (const float*)d_in[25];
    const float* rescale = (const float*)d_in[26];

    char* wsb = (char*)d_ws;
    short* wt   = (short*)wsb;                                 // 86016 shorts
    short* kpx  = (short*)(wsb + (1u << 20));                  // 8 MB  [n][64]
    short* vpx  = (short*)(wsb + (1u << 20) + (8u << 20));     // 8 MB
    float* xmf  = (float*)(wsb + (1u << 20) + (16u << 20));    // 16 MB fp32
    short* qpx  = (short*)(wsb + (1u << 20) + (32u << 20));    // 8 MB
    float* gram = (float*)(wsb + (1u << 20) + (40u << 20));    // 4096 f32
    float* nsq  = gram + 4096;                                 // 512 f32
    short* MT   = (short*)(nsq + 512);                         // 16384 shorts

    dim3 blk(256);
    k_prep<<<dim3(336), blk, 0, stream>>>(wa, wb, in_w, w1, w2, w3, wq, wk, wv, wt);
    hipMemsetAsync(gram, 0, (4096 + 512) * sizeof(float), stream);
    k_fyk<<<dim3(1024), blk, 0, stream>>>(x, sem, ba, bbv, in_b, bk, bv, wt, kpx, vpx);
    k_mlp<<<dim3(1024), blk, 0, stream>>>(x, b1, g1, be1, b2, g2, be2, b3, bq, wt, xmf, qpx);
    k_gram<<<dim3(512), blk, 0, stream>>>(qpx, kpx, gram, nsq);
    k_attnM<<<dim3(4), blk, 0, stream>>>(gram, nsq, rescale, wo, MT);
    k_out<<<dim3(1024), blk, 0, stream>>>(vpx, xmf, MT, bo, (float*)d_out);
}

// Round 6
// 193.469 us; speedup vs baseline: 1.3065x; 1.3065x over previous
//
#include <hip/hip_runtime.h>
#include <hip/hip_bf16.h>

#define NPX 16384
typedef __attribute__((ext_vector_type(8))) short short8;
typedef __attribute__((ext_vector_type(8))) _Float16 half8;
typedef __attribute__((ext_vector_type(4))) float f32x4;

#define DEV static __device__ __forceinline__

// wt layout (fp16 shorts)
#define WAB   0
#define WINW  4096
#define W1T   8192
#define W2T   16384
#define W3T   32768
#define WQT   40960
#define WKV   45056
#define WTOT  53248

DEV float lrelu(float v) { return v >= 0.f ? v : 0.01f * v; }
DEV short f2h(float f) { _Float16 h = (_Float16)f; return __builtin_bit_cast(short, h); }
DEV float h2f(short s) { return (float)__builtin_bit_cast(_Float16, s); }
DEV f32x4 mfmah(half8 a, half8 b, f32x4 c) {
    return __builtin_amdgcn_mfma_f32_16x16x32_f16(a, b, c, 0, 0, 0);
}

// ---------------------------------------------------------------------------
// M m-tiles (16 px each) GEMM: acc[m][t] += A[(m*16+row)][k] * WT[t*16+col][k]
// A: fp16 raw shorts, wave-private LDS (or global), row pitch `pitch`.
// WT: fp16 [e][K] global (L2-hot). B-fragment shared across all M tiles.
// ---------------------------------------------------------------------------
template<int K, int NT, int M>
DEV void gemmM(const short* __restrict__ A, int pitch,
               const short* __restrict__ WT, f32x4 (&acc)[M][NT])
{
    int lane = threadIdx.x & 63;
    int ln = lane & 15, q8 = (lane >> 4) * 8;
    const short* bp = WT + ln * K + q8;
#pragma unroll
    for (int c0 = 0; c0 < K; c0 += 32) {
        half8 a[M];
#pragma unroll
        for (int m = 0; m < M; ++m)
            a[m] = *(const half8*)(A + (size_t)(m * 16 + ln) * pitch + q8 + c0);
#pragma unroll
        for (int t = 0; t < NT; ++t) {
            half8 b = *(const half8*)(bp + (size_t)t * 16 * K + c0);
#pragma unroll
            for (int m = 0; m < M; ++m) acc[m][t] = mfmah(a[m], b, acc[m][t]);
        }
    }
}

template<int NT, int M>
DEV void acc_biasM(f32x4 (&acc)[M][NT], const float* __restrict__ bias)
{
    int ln = threadIdx.x & 15;
#pragma unroll
    for (int t = 0; t < NT; ++t) {
        float bv = bias[t * 16 + ln];
        f32x4 v = {bv, bv, bv, bv};
#pragma unroll
        for (int m = 0; m < M; ++m) acc[m][t] = v;
    }
}

// D layout: col=lane&15, row=(lane>>4)*4+reg -> LDS [m*16+row][pitch] fp16
template<int NT, int M>
DEV void dstoreM(const f32x4 (&acc)[M][NT], short* sD, int pitch)
{
    int lane = threadIdx.x & 63;
    int ln = lane & 15, r0 = (lane >> 4) * 4;
#pragma unroll
    for (int m = 0; m < M; ++m)
#pragma unroll
        for (int t = 0; t < NT; ++t)
#pragma unroll
            for (int r = 0; r < 4; ++r)
                sD[(m * 16 + r0 + r) * pitch + t * 16 + ln] = f2h(acc[m][t][r]);
}

// in-register LayerNorm(+lrelu) over 128 channels, per m-tile, fp32 stats
template<int NT, int M>
DEV void ln_regM(f32x4 (&acc)[M][NT], const float* __restrict__ g, const float* __restrict__ be)
{
    int lane = threadIdx.x & 63, ln = lane & 15;
#pragma unroll
    for (int m = 0; m < M; ++m) {
        f32x4 s = {0,0,0,0}, ss = {0,0,0,0};
#pragma unroll
        for (int t = 0; t < NT; ++t)
#pragma unroll
            for (int r = 0; r < 4; ++r) { float v = acc[m][t][r]; s[r] += v; ss[r] += v * v; }
#pragma unroll
        for (int off = 1; off < 16; off <<= 1)
#pragma unroll
            for (int r = 0; r < 4; ++r) {
                s[r] += __shfl_xor(s[r], off);
                ss[r] += __shfl_xor(ss[r], off);
            }
        f32x4 mm, rs;
#pragma unroll
        for (int r = 0; r < 4; ++r) {
            float mean = s[r] * (1.f / 128.f);
            float var = ss[r] * (1.f / 128.f) - mean * mean;
            mm[r] = mean; rs[r] = rsqrtf(var + 1e-5f);
        }
#pragma unroll
        for (int t = 0; t < NT; ++t) {
            float gg = g[t * 16 + ln], bb = be[t * 16 + ln];
#pragma unroll
            for (int r = 0; r < 4; ++r)
                acc[m][t][r] = lrelu((acc[m][t][r] - mm[r]) * rs[r] * gg + bb);
        }
    }
}

// wave-level copyout of ROWSx64 fp16 tile -> global [px][64]
template<int ROWS>
DEV void copyoutR(const short* sD, int pitch, short* __restrict__ dst)
{
    int lane = threadIdx.x & 63;
#pragma unroll
    for (int it = 0; it < ROWS / 8; ++it) {
        int idx = it * 512 + lane * 8;
        int px = idx >> 6, c = idx & 63;
        short8 v = *(const short8*)(&sD[px * pitch + c]);
        *reinterpret_cast<short8*>(dst + (size_t)px * 64 + c) = v;
    }
}

// stage 32 px of x (fp32 channel-major) -> wave LDS [32][72] fp16
DEV void stage_x32(const float* __restrict__ xb, int n0, short* X)
{
    int lane = threadIdx.x & 63;
    int ln = lane & 15, qd = lane >> 4;
#pragma unroll
    for (int m = 0; m < 2; ++m) {
        float vb[16];
#pragma unroll
        for (int t = 0; t < 16; ++t)
            vb[t] = xb[(size_t)(qd * 16 + t) * NPX + n0 + m * 16 + ln];
        short8 lo, hi;
#pragma unroll
        for (int t = 0; t < 8; ++t) { lo[t] = f2h(vb[t]); hi[t] = f2h(vb[8 + t]); }
        *reinterpret_cast<short8*>(&X[(m * 16 + ln) * 72 + qd * 16]) = lo;
        *reinterpret_cast<short8*>(&X[(m * 16 + ln) * 72 + qd * 16 + 8]) = hi;
    }
}

// ---------------------------------------------------------------------------
// k_prep: transposed fp16 weights WT[e][k]
// ---------------------------------------------------------------------------
__global__ __launch_bounds__(256) void k_prep(const float* __restrict__ wa,
                                              const float* __restrict__ wb,
                                              const float* __restrict__ in_w,
                                              const float* __restrict__ w1,
                                              const float* __restrict__ w2,
                                              const float* __restrict__ w3,
                                              const float* __restrict__ wq,
                                              const float* __restrict__ wk,
                                              const float* __restrict__ wv,
                                              short* __restrict__ wt)
{
    int idx = blockIdx.x * 256 + threadIdx.x;
    if (idx >= WTOT) return;
    float v;
    if (idx < WINW) {
        int j = idx >> 6, c = idx & 63;
        v = (j < 4) ? wa[c * 4 + j] : wb[((j - 4) / 3) * 192 + c * 3 + ((j - 4) % 3)];
    } else if (idx < W1T) {
        int i = idx - WINW; v = in_w[(i & 63) * 64 + (i >> 6)];
    } else if (idx < W2T) {
        int i = idx - W1T; v = w1[(i & 63) * 128 + (i >> 6)];
    } else if (idx < W3T) {
        int i = idx - W2T; v = w2[(i & 127) * 128 + (i >> 7)];
    } else if (idx < WQT) {
        int i = idx - W3T; v = w3[(i & 127) * 64 + (i >> 7)];
    } else if (idx < WKV) {
        int i = idx - WQT; v = wq[(i & 63) * 64 + (i >> 6)];
    } else {
        int i = idx - WKV; int e = i >> 6, k = i & 63;
        v = (e < 64) ? wk[k * 64 + e] : wv[k * 64 + (e - 64)];
    }
    wt[idx] = f2h(v);
}

// ---------------------------------------------------------------------------
// k_fyk: x,sem -> feat -> y -> k,v   (barrier-free, 32 px/wave, fp16)
// ---------------------------------------------------------------------------
__global__ __launch_bounds__(256) void k_fyk(const float* __restrict__ x,
                                             const float* __restrict__ sem,
                                             const float* __restrict__ ba,
                                             const float* __restrict__ bbv,
                                             const float* __restrict__ in_b,
                                             const float* __restrict__ bk,
                                             const float* __restrict__ bv,
                                             const short* __restrict__ wt,
                                             short* __restrict__ kout,
                                             short* __restrict__ vout)
{
    __shared__ short smem[4][3][32 * 72];
    int tid = threadIdx.x, w = tid >> 6, lane = tid & 63;
    int ln = lane & 15, qd = lane >> 4, r0 = qd * 4;
    int pw = blockIdx.x * 128 + w * 32;
    int b = pw >> 14, n0 = pw & (NPX - 1);
    const float* xb = x + (size_t)b * 64 * NPX;
    short* X  = smem[w][0];
    short* S1 = smem[w][1];
    short* S2 = smem[w][2];

    stage_x32(xb, n0, X);

    f32x4 a1[2][4];
    { f32x4 z = {0,0,0,0};
      for (int m = 0; m < 2; ++m) for (int t = 0; t < 4; ++t) a1[m][t] = z; }
    gemmM<64, 4, 2>(X, 72, wt + WAB, a1);
#pragma unroll
    for (int m = 0; m < 2; ++m)
#pragma unroll
        for (int t = 0; t < 4; ++t) {
            int j = t * 16 + ln;
            int cls = (j < 4) ? 0 : 1 + (j - 4) / 3;
            float bias = (j < 4) ? ba[j] : bbv[j - 4];
            f32x4 sm4 = *(const f32x4*)(sem + ((size_t)b * 21 + cls) * NPX + n0 + m * 16 + r0);
#pragma unroll
            for (int r = 0; r < 4; ++r)
                S1[(m * 16 + r0 + r) * 72 + j] = f2h(fmaxf(sm4[r], 0.f) * a1[m][t][r] + bias);
        }

    f32x4 a2[2][4];
    acc_biasM<4, 2>(a2, in_b);
    gemmM<64, 4, 2>(S1, 72, wt + WINW, a2);
    dstoreM<4, 2>(a2, S2, 72);

    f32x4 a3[2][8];
    {
#pragma unroll
        for (int t = 0; t < 8; ++t) {
            float bvv = (t < 4) ? bk[t * 16 + ln] : bv[(t - 4) * 16 + ln];
            f32x4 vv = {bvv, bvv, bvv, bvv};
            a3[0][t] = vv; a3[1][t] = vv;
        }
    }
    gemmM<64, 8, 2>(S2, 72, wt + WKV, a3);
#pragma unroll
    for (int m = 0; m < 2; ++m)
#pragma unroll
        for (int t = 0; t < 8; ++t)
#pragma unroll
            for (int r = 0; r < 4; ++r) {
                short hv = f2h(a3[m][t][r]);
                if (t < 4) S1[(m * 16 + r0 + r) * 72 + t * 16 + ln] = hv;
                else       X [(m * 16 + r0 + r) * 72 + (t - 4) * 16 + ln] = hv;
            }
    copyoutR<32>(S1, 72, kout + (size_t)pw * 64);
    copyoutR<32>(X, 72, vout + (size_t)pw * 64);
}

// ---------------------------------------------------------------------------
// k_mlp: x -> h1 -> h2 -> xm(fp16) -> q   (barrier-free, 32 px/wave, fp16)
// ---------------------------------------------------------------------------
__global__ __launch_bounds__(256) void k_mlp(const float* __restrict__ x,
                                             const float* __restrict__ b1,
                                             const float* __restrict__ g1,
                                             const float* __restrict__ be1,
                                             const float* __restrict__ b2,
                                             const float* __restrict__ g2,
                                             const float* __restrict__ be2,
                                             const float* __restrict__ b3,
                                             const float* __restrict__ bq,
                                             const short* __restrict__ wt,
                                             short* __restrict__ xmout,
                                             short* __restrict__ qout)
{
    __shared__ short sX[4][32 * 72];
    __shared__ short sS[4][32 * 136];
    int tid = threadIdx.x, w = tid >> 6;
    int pw = blockIdx.x * 128 + w * 32;
    int b = pw >> 14, n0 = pw & (NPX - 1);
    const float* xb = x + (size_t)b * 64 * NPX;
    short* X = sX[w];
    short* S = sS[w];

    stage_x32(xb, n0, X);

    f32x4 acc[2][8];
    acc_biasM<8, 2>(acc, b1);
    gemmM<64, 8, 2>(X, 72, wt + W1T, acc);
    ln_regM<8, 2>(acc, g1, be1);
    dstoreM<8, 2>(acc, S, 136);

    acc_biasM<8, 2>(acc, b2);
    gemmM<128, 8, 2>(S, 136, wt + W2T, acc);
    ln_regM<8, 2>(acc, g2, be2);
    dstoreM<8, 2>(acc, S, 136);

    f32x4 a3[2][4];
    acc_biasM<4, 2>(a3, b3);
    gemmM<128, 4, 2>(S, 136, wt + W3T, a3);
    dstoreM<4, 2>(a3, X, 72);
    copyoutR<32>(X, 72, xmout + (size_t)pw * 64);

    f32x4 aq[2][4];
    acc_biasM<4, 2>(aq, bq);
    gemmM<64, 4, 2>(X, 72, wt + WQT, aq);
    dstoreM<4, 2>(aq, S, 136);
    copyoutR<32>(S, 136, qout + (size_t)pw * 64);
}

// ---------------------------------------------------------------------------
// k_gram: per-wave 128-px chunk; 3 MFMAs (qk, qq, kk); fp32 atomics
// ---------------------------------------------------------------------------
__global__ __launch_bounds__(256) void k_gram(const short* __restrict__ q,
                                              const short* __restrict__ k,
                                              float* __restrict__ gram,
                                              float* __restrict__ nsq)
{
    __shared__ short sQ[4][16 * 136], sK[4][16 * 136];
    int tid = threadIdx.x, w = tid >> 6, lane = tid & 63;
    int ln = lane & 15, q8 = (lane >> 4) * 8, qd = lane >> 4;
    int bh = blockIdx.x >> 5;
    int b = bh >> 2, h = bh & 3;
    int nb = (blockIdx.x & 31) * 512 + w * 128;
    size_t pxg = (size_t)b * NPX + nb;

#pragma unroll
    for (int it = 0; it < 4; ++it) {
        int idx = it * 64 + lane;
        int px = idx >> 1, half = idx & 1;
        short8 qv = *(const short8*)(q + (pxg + px) * 64 + h * 16 + half * 8);
        short8 kv = *(const short8*)(k + (pxg + px) * 64 + h * 16 + half * 8);
#pragma unroll
        for (int j = 0; j < 8; ++j) {
            sQ[w][(half * 8 + j) * 136 + px] = qv[j];
            sK[w][(half * 8 + j) * 136 + px] = kv[j];
        }
    }

    f32x4 aqk = {0,0,0,0}, aqq = {0,0,0,0}, akk = {0,0,0,0};
#pragma unroll
    for (int s = 0; s < 4; ++s) {
        half8 a  = *(const half8*)(&sQ[w][ln * 136 + s * 32 + q8]);
        half8 bb = *(const half8*)(&sK[w][ln * 136 + s * 32 + q8]);
        aqk = mfmah(a, bb, aqk);
        aqq = mfmah(a, a, aqq);
        akk = mfmah(bb, bb, akk);
    }
    int e = ln;
#pragma unroll
    for (int r = 0; r < 4; ++r) {
        int d = qd * 4 + r;
        atomicAdd(&gram[bh * 256 + d * 16 + e], aqk[r]);
        if (e == d) {
            atomicAdd(&nsq[bh * 16 + d], aqq[r]);
            atomicAdd(&nsq[256 + bh * 16 + d], akk[r]);
        }
    }
}

// ---------------------------------------------------------------------------
// k_attnM: softmax + fold wo -> MT[b][cc][he] fp16
// ---------------------------------------------------------------------------
__global__ __launch_bounds__(256) void k_attnM(const float* __restrict__ gram,
                                               const float* __restrict__ nsq,
                                               const float* __restrict__ rescale,
                                               const float* __restrict__ wo,
                                               short* __restrict__ MT)
{
    __shared__ float s_at[1024];
    int b = blockIdx.x, tid = threadIdx.x;
    if (tid < 64) {
        int h = tid >> 4, d = tid & 15;
        float nq = sqrtf(nsq[b * 64 + h * 16 + d]) + 1e-8f;
        float rsc = rescale[h];
        float lg[16];
#pragma unroll
        for (int e = 0; e < 16; ++e) {
            float nk = sqrtf(nsq[256 + b * 64 + h * 16 + e]) + 1e-8f;
            lg[e] = rsc * gram[b * 1024 + h * 256 + d * 16 + e] / (nq * nk);
        }
        float m = lg[0];
#pragma unroll
        for (int e = 1; e < 16; ++e) m = fmaxf(m, lg[e]);
        float ssum = 0.f;
#pragma unroll
        for (int e = 0; e < 16; ++e) { lg[e] = expf(lg[e] - m); ssum += lg[e]; }
        float inv = 1.f / ssum;
#pragma unroll
        for (int e = 0; e < 16; ++e) s_at[h * 256 + d * 16 + e] = lg[e] * inv;
    }
    __syncthreads();
    int he = tid >> 2, h = he >> 4, e = he & 15;
    int cc0 = (tid & 3) * 16;
#pragma unroll
    for (int cx = 0; cx < 16; ++cx) {
        int cc = cc0 + cx;
        float s = 0.f;
#pragma unroll
        for (int d = 0; d < 16; ++d)
            s = fmaf(s_at[h * 256 + d * 16 + e], wo[(h * 16 + d) * 64 + cc], s);
        MT[b * 4096 + cc * 64 + he] = f2h(s);
    }
}

// ---------------------------------------------------------------------------
// k_out: out[b][c][n] = v@M + bo + xm   (barrier-free, no LDS, 16 px/wave)
// ---------------------------------------------------------------------------
__global__ __launch_bounds__(256) void k_out(const short* __restrict__ v,
                                             const short* __restrict__ xm,
                                             const short* __restrict__ MT,
                                             const float* __restrict__ bo,
                                             float* __restrict__ out)
{
    int tid = threadIdx.x, w = tid >> 6, lane = tid & 63;
    int ln = lane & 15, qd = lane >> 4;
    int pw = blockIdx.x * 64 + w * 16;
    int b = pw >> 14, n0 = pw & (NPX - 1);

    f32x4 acc[1][4];
    acc_biasM<4, 1>(acc, bo);
    gemmM<64, 4, 1>(v + (size_t)pw * 64, 64, MT + b * 4096, acc);

#pragma unroll
    for (int t = 0; t < 4; ++t) {
        int c = t * 16 + ln;
        f32x4 o;
#pragma unroll
        for (int r = 0; r < 4; ++r)
            o[r] = acc[0][t][r] + h2f(xm[(size_t)(pw + qd * 4 + r) * 64 + c]);
        *reinterpret_cast<f32x4*>(out + ((size_t)b * 64 + c) * NPX + n0 + qd * 4) = o;
    }
}

// ---------------------------------------------------------------------------
extern "C" void kernel_launch(void* const* d_in, const int* in_sizes, int n_in,
                              void* d_out, int out_size, void* d_ws, size_t ws_size,
                              hipStream_t stream)
{
    const float* x    = (const float*)d_in[0];
    const float* sem  = (const float*)d_in[1];
    const float* wa   = (const float*)d_in[2];
    const float* ba   = (const float*)d_in[3];
    const float* wb   = (const float*)d_in[4];
    const float* bbv  = (const float*)d_in[5];
    const float* in_w = (const float*)d_in[6];
    const float* in_b = (const float*)d_in[7];
    const float* w1   = (const float*)d_in[8];
    const float* b1   = (const float*)d_in[9];
    const float* g1   = (const float*)d_in[10];
    const float* be1  = (const float*)d_in[11];
    const float* w2   = (const float*)d_in[12];
    const float* b2   = (const float*)d_in[13];
    const float* g2   = (const float*)d_in[14];
    const float* be2  = (const float*)d_in[15];
    const float* w3   = (const float*)d_in[16];
    const float* b3   = (const float*)d_in[17];
    const float* wq   = (const float*)d_in[18];
    const float* bq   = (const float*)d_in[19];
    const float* wk   = (const float*)d_in[20];
    const float* bk   = (const float*)d_in[21];
    const float* wv   = (const float*)d_in[22];
    const float* bv   = (const float*)d_in[23];
    const float* wo   = (const float*)d_in[24];
    const float* bo   = (const float*)d_in[25];
    const float* rescale = (const float*)d_in[26];

    char* wsb = (char*)d_ws;
    short* wt   = (short*)wsb;                                 // 53248 shorts
    short* kpx  = (short*)(wsb + (1u << 20));                  // 8 MB  [n][64] fp16
    short* vpx  = (short*)(wsb + (1u << 20) + (8u << 20));     // 8 MB
    short* xmp  = (short*)(wsb + (1u << 20) + (16u << 20));    // 8 MB
    short* qpx  = (short*)(wsb + (1u << 20) + (24u << 20));    // 8 MB
    float* gram = (float*)(wsb + (1u << 20) + (32u << 20));    // 4096 f32
    float* nsq  = gram + 4096;                                 // 512 f32
    short* MT   = (short*)(nsq + 512);                         // 16384 shorts

    dim3 blk(256);
    k_prep<<<dim3(208), blk, 0, stream>>>(wa, wb, in_w, w1, w2, w3, wq, wk, wv, wt);
    hipMemsetAsync(gram, 0, (4096 + 512) * sizeof(float), stream);
    k_fyk<<<dim3(512), blk, 0, stream>>>(x, sem, ba, bbv, in_b, bk, bv, wt, kpx, vpx);
    k_mlp<<<dim3(512), blk, 0, stream>>>(x, b1, g1, be1, b2, g2, be2, b3, bq, wt, xmp, qpx);
    k_gram<<<dim3(512), blk, 0, stream>>>(qpx, kpx, gram, nsq);
    k_attnM<<<dim3(4), blk, 0, stream>>>(gram, nsq, rescale, wo, MT);
    k_out<<<dim3(1024), blk, 0, stream>>>(vpx, xmp, MT, bo, (float*)d_out);
}